// Round 10
// baseline (203.834 us; speedup 1.0000x reference)
//
#include <hip/hip_runtime.h>

#define GRID_H 20
#define GRID_W 80
#define NCH 264
#define NPIX 128   // 16x8 glyph pixels

typedef __attribute__((ext_vector_type(8))) short short8;
typedef __attribute__((ext_vector_type(4))) float f32x4;
typedef __attribute__((ext_vector_type(8))) unsigned short u16x8;

static __device__ __forceinline__ unsigned short f2bf(float f) {
    unsigned int u = __builtin_bit_cast(unsigned int, f);
    u += 0x7FFFu + ((u >> 16) & 1u);   // round-to-nearest-even
    return (unsigned short)(u >> 16);
}

// Pack cm (f32 [256 ch][128 px]) -> ws (bf16 [128 px][256 ch], linear).
__global__ void prep_kernel(const float* __restrict__ cm,
                            unsigned short* __restrict__ ws) {
    int i = blockIdx.x * 256 + threadIdx.x;   // 0..4095
    int p  = i & 127;
    int c8 = i >> 7;                          // channel-group of 8 (0..31)
    u16x8 pk;
    #pragma unroll
    for (int j = 0; j < 8; ++j) pk[j] = f2bf(cm[(c8 * 8 + j) * NPIX + p]);
    *reinterpret_cast<u16x8*>((char*)ws + p * 512 + c8 * 16) = pk;
}

// NOTE: plain 1-arg launch_bounds only. The 2-arg form (min waves/EU)
// miscompiled MFMA accumulation in R2/R3/R7.
template <bool USE_WS>
__global__ __launch_bounds__(320) void ansi_kernel(
        const float* __restrict__ data,
        const float* __restrict__ cm,
        const unsigned short* __restrict__ ws,
        float* __restrict__ out) {
    // Wave-PRIVATE epilogue staging (R9-proven): [wave][line][cell-slot][x*3+ch]
    __shared__ alignas(16) float S[5][2][16][24];
    // Wave-private fg/bg: [wave][local cell][bg.rgb, diff.rgb, pad2]
    __shared__ float fgbgW[5][16][8];
    // ZERO __syncthreads in this kernel: all LDS producer/consumer pairs are
    // within one wave (in-order), waves run fully independent.

    const int blk = blockIdx.x;
    const int b = blk / GRID_H;
    const int h = blk % GRID_H;
    const float* dbase = data + (size_t)(b * GRID_H + h) * GRID_W * NCH;
    const int t = threadIdx.x;
    const int wave = t >> 6;
    const int lane = t & 63;
    const int mrow = lane & 15;     // cell within M-tile / pixel within N-tile
    const int g    = lane >> 4;     // k-group
    const int cell0 = wave * 16;

    // ---- wave-private fg/bg stage: lanes 0..15 each handle one cell ----
    if (lane < 16) {
        const float* q = dbase + (size_t)(cell0 + lane) * NCH + 256;
        float4 a = *reinterpret_cast<const float4*>(q);      // fg_bold, fg.rgb
        float4 c = *reinterpret_cast<const float4*>(q + 4);  // bg_bold, bg.rgb
        float fs = 0.5f * a.x + 0.5f;
        float bs = 0.5f * c.x + 0.5f;
        float bgr = bs * c.y, bgg = bs * c.z, bgb = bs * c.w;
        float* o = &fgbgW[wave][lane][0];
        o[0] = bgr; o[1] = bgg; o[2] = bgb;
        o[3] = fs * a.y - bgr; o[4] = fs * a.z - bgg; o[5] = fs * a.w - bgb;
    }

    // ---- load + pack A once (full K=256): 8 x bf16x8 ----
    const float* arow = dbase + (size_t)(cell0 + mrow) * NCH + g * 8;
    short8 apk[8];
    #pragma unroll
    for (int ks = 0; ks < 8; ++ks) {
        float4 a0 = *reinterpret_cast<const float4*>(arow + ks * 32);
        float4 a1 = *reinterpret_cast<const float4*>(arow + ks * 32 + 4);
        u16x8 ap;
        ap[0] = f2bf(a0.x); ap[1] = f2bf(a0.y); ap[2] = f2bf(a0.z); ap[3] = f2bf(a0.w);
        ap[4] = f2bf(a1.x); ap[5] = f2bf(a1.y); ap[6] = f2bf(a1.z); ap[7] = f2bf(a1.w);
        apk[ks] = __builtin_bit_cast(short8, ap);
    }

    f32x4 acc[8];
    #pragma unroll
    for (int n = 0; n < 8; ++n) acc[n] = (f32x4){0.f, 0.f, 0.f, 0.f};

    // ---- GEMM: B-fragments straight from L1/L2-resident ws into registers.
    // Same fragment convention as R1..R9 (contiguous-k per lane; A and B
    // identical convention so internal K-permutation cancels).
    const char* wsb = (const char*)ws;
    #pragma unroll
    for (int ks = 0; ks < 8; ++ks) {
        const int k0 = ks * 32 + g * 8;
        short8 bf[8];
        #pragma unroll
        for (int n = 0; n < 8; ++n) {
            int p = n * 16 + mrow;
            if (USE_WS) {
                bf[n] = *reinterpret_cast<const short8*>(wsb + p * 512 + k0 * 2);
            } else {
                u16x8 pk;
                #pragma unroll
                for (int j = 0; j < 8; ++j) pk[j] = f2bf(cm[(k0 + j) * NPIX + p]);
                bf[n] = __builtin_bit_cast(short8, pk);
            }
        }
        #pragma unroll
        for (int n = 0; n < 8; ++n)
            acc[n] = __builtin_amdgcn_mfma_f32_16x16x32_bf16(apk[ks], bf[n],
                                                             acc[n], 0, 0, 0);
    }

    // ---- epilogue (R9-proven): wave-private LDS transpose, zero barriers ----
    const int col = lane & 15;

    float bgv[4][3], dv[4][3];
    #pragma unroll
    for (int r = 0; r < 4; ++r) {
        const float* fb = &fgbgW[wave][g * 4 + r][0];
        bgv[r][0] = fb[0]; bgv[r][1] = fb[1]; bgv[r][2] = fb[2];
        dv[r][0]  = fb[3]; dv[r][1]  = fb[4]; dv[r][2]  = fb[5];
    }

    float4* out4 = (float4*)out;
    const size_t rowf4 = (size_t)(b * 320 + h * 16) * 480 + wave * 96;
    const int line_sel = col >> 3;          // which y-line this lane's acc feeds
    const int x3 = (col & 7) * 3;

    #pragma unroll
    for (int pass = 0; pass < 8; ++pass) {
        // acc[pass] covers pixels pass*16..pass*16+15 = y-lines {2p, 2p+1}
        #pragma unroll
        for (int r = 0; r < 4; ++r) {
            float raw = acc[pass][r];
            float* o = &S[wave][line_sel][r * 4 + g][x3];
            o[0] = bgv[r][0] + raw * dv[r][0];
            o[1] = bgv[r][1] + raw * dv[r][1];
            o[2] = bgv[r][2] + raw * dv[r][2];
        }
        // readback (b128, permuted cell slot) + coalesced global store
        const float4* Sw = (const float4*)&S[wave][0][0][0];   // 192 float4
        #pragma unroll
        for (int q = 0; q < 3; ++q) {
            int j = q * 64 + lane;            // 0..191
            int line = (j >= 96) ? 1 : 0;
            int rem = j - 96 * line;          // 0..95 = cell*6 + s
            int c = rem / 6;
            int s = rem - 6 * c;
            float4 v = Sw[line * 96 + ((c & 3) * 4 + (c >> 2)) * 6 + s];
            out4[rowf4 + (size_t)(pass * 2 + line) * 480 + rem] = v;
        }
    }
}

extern "C" void kernel_launch(void* const* d_in, const int* in_sizes, int n_in,
                              void* d_out, int out_size, void* d_ws, size_t ws_size,
                              hipStream_t stream) {
    (void)in_sizes; (void)n_in; (void)out_size;
    const float* data = (const float*)d_in[0];
    const float* cm   = (const float*)d_in[1];
    float* out        = (float*)d_out;
    const int nblocks = 128 * GRID_H;   // one block per (b, h)
    if (ws_size >= 65536) {
        prep_kernel<<<16, 256, 0, stream>>>(cm, (unsigned short*)d_ws);
        ansi_kernel<true><<<nblocks, 320, 0, stream>>>(
            data, cm, (const unsigned short*)d_ws, out);
    } else {
        ansi_kernel<false><<<nblocks, 320, 0, stream>>>(data, cm, nullptr, out);
    }
}